// Round 4
// baseline (29.439 us; speedup 1.0000x reference)
//
#include <hip/hip_runtime.h>

#define NPTS 524288
#define HID 100

// Per-j constant table (two float4 per j, 32B):
//   tab[2j]   = { w1x*2log2e, w1y*2log2e, b1*2log2e, ku }
//   tab[2j+1] = { kv, 0, 0, 0 }
// where ku = 2*W2*w1y*(w1x - w1y)  (u = Hxy - Hyy accumulates s*ku)
//       kv = 2*W2*w1x*(w1y - w1x)  (v = Hxy - Hxx accumulates s*kv)
__global__ void kDivFree_prep(const float* __restrict__ W1,
                              const float* __restrict__ b1,
                              const float* __restrict__ W2,
                              float4* __restrict__ tab) {
    int j = threadIdx.x;
    if (j < HID) {
        const float L2E2 = 2.8853900817779268f;  // 2*log2(e)
        float w1x = W1[j];          // W1[0][j], W1 is [2,HID] row-major
        float w1y = W1[HID + j];    // W1[1][j]
        float w2  = W2[j];
        float ku = 2.0f * w2 * w1y * (w1x - w1y);
        float kv = 2.0f * w2 * w1x * (w1y - w1x);
        tab[2 * j]     = make_float4(w1x * L2E2, w1y * L2E2, b1[j] * L2E2, ku);
        tab[2 * j + 1] = make_float4(kv, 0.0f, 0.0f, 0.0f);
    }
}

__device__ __forceinline__ float fexp2(float x) {
    float r;
    asm("v_exp_f32 %0, %1" : "=v"(r) : "v"(x));
    return r;
}

__global__ void __launch_bounds__(256)
kDivFree_main(const float2* __restrict__ xy,
              const float4* __restrict__ tab,
              float2* __restrict__ out) {
    int i = blockIdx.x * blockDim.x + threadIdx.x;
    float2 p = xy[i];
    float u = 0.0f, v = 0.0f;
#pragma unroll 10
    for (int j = 0; j < HID; ++j) {
        float4 A = tab[2 * j];
        float4 K = tab[2 * j + 1];
        // a' = 2*log2(e) * (x*w1x + y*w1y + b1)
        float a = fmaf(p.x, A.x, fmaf(p.y, A.y, A.z));
        float t = fexp2(a);                       // e^{2a}
        float r = __builtin_amdgcn_rcpf(t + 1.0f);
        float h = fmaf(-2.0f, r, 1.0f);           // tanh(a) = 1 - 2/(t+1)
        float hm = fmaf(h, h, -1.0f);             // h^2 - 1
        float s = h * hm;                         // h^3 - h
        u = fmaf(s, A.w, u);
        v = fmaf(s, K.x, v);
    }
    out[i] = make_float2(u, v);
}

extern "C" void kernel_launch(void* const* d_in, const int* in_sizes, int n_in,
                              void* d_out, int out_size, void* d_ws, size_t ws_size,
                              hipStream_t stream) {
    // inputs: 0=f (unused), 1=xy, 2=W1, 3=b1, 4=W2, 5=b2 (unused: Hessian kills it)
    const float* xy = (const float*)d_in[1];
    const float* W1 = (const float*)d_in[2];
    const float* b1 = (const float*)d_in[3];
    const float* W2 = (const float*)d_in[4];
    float4* tab = (float4*)d_ws;  // needs 100*32 = 3200 bytes

    kDivFree_prep<<<1, 128, 0, stream>>>(W1, b1, W2, tab);
    kDivFree_main<<<NPTS / 256, 256, 0, stream>>>((const float2*)xy, tab,
                                                  (float2*)d_out);
}

// Round 5
// 27.284 us; speedup vs baseline: 1.0790x; 1.0790x over previous
//
#include <hip/hip_runtime.h>

#define NPTS 524288
#define HID 100
#define PPT 2      // points per thread: amortizes per-j table loads
#define BLK 256

// tabA[j] = { w1x*2log2e, w1y*2log2e, b1*2log2e, ku }   (1600 B)
// tabK[j] = kv, loaded as float4 per 4 j's              (400 B)
// ku = 2*W2*w1y*(w1x - w1y)   (u = Hxy - Hyy)
// kv = 2*W2*w1x*(w1y - w1x)   (v = Hxy - Hxx)
__global__ void kDivFree_prep(const float* __restrict__ W1,
                              const float* __restrict__ b1,
                              const float* __restrict__ W2,
                              float4* __restrict__ tabA,
                              float*  __restrict__ tabK) {
    int j = threadIdx.x;
    if (j < HID) {
        const float L2E2 = 2.8853900817779268f;  // 2*log2(e)
        float w1x = W1[j];          // W1[0][j]
        float w1y = W1[HID + j];    // W1[1][j]
        float w2  = W2[j];
        float ku = 2.0f * w2 * w1y * (w1x - w1y);
        float kv = 2.0f * w2 * w1x * (w1y - w1x);
        tabA[j] = make_float4(w1x * L2E2, w1y * L2E2, b1[j] * L2E2, ku);
        tabK[j] = kv;
    }
}

__device__ __forceinline__ float fexp2(float x) {
    float r;
    asm("v_exp_f32 %0, %1" : "=v"(r) : "v"(x));
    return r;
}

__device__ __forceinline__ float tanh_s(float a2l) {
    // input is 2*log2(e)*a; returns s = h^3 - h where h = tanh(a)
    float t = fexp2(a2l);                        // e^{2a}
    float r = __builtin_amdgcn_rcpf(t + 1.0f);
    float h = fmaf(-2.0f, r, 1.0f);              // tanh
    return h * fmaf(h, h, -1.0f);                // h^3 - h
}

__global__ void __launch_bounds__(BLK)
kDivFree_main(const float2* __restrict__ xy,
              const float4* __restrict__ tabA,
              const float4* __restrict__ tabK4,
              float2* __restrict__ out) {
    int base = blockIdx.x * (BLK * PPT) + threadIdx.x;
    float2 p0 = xy[base];
    float2 p1 = xy[base + BLK];
    float u0 = 0.f, v0 = 0.f, u1 = 0.f, v1 = 0.f;
#pragma unroll 5
    for (int j4 = 0; j4 < HID / 4; ++j4) {
        float4 K = tabK4[j4];
        float kv[4] = {K.x, K.y, K.z, K.w};
#pragma unroll
        for (int jj = 0; jj < 4; ++jj) {
            float4 A = tabA[j4 * 4 + jj];
            float s0 = tanh_s(fmaf(p0.x, A.x, fmaf(p0.y, A.y, A.z)));
            u0 = fmaf(s0, A.w, u0);
            v0 = fmaf(s0, kv[jj], v0);
            float s1 = tanh_s(fmaf(p1.x, A.x, fmaf(p1.y, A.y, A.z)));
            u1 = fmaf(s1, A.w, u1);
            v1 = fmaf(s1, kv[jj], v1);
        }
    }
    out[base]       = make_float2(u0, v0);
    out[base + BLK] = make_float2(u1, v1);
}

extern "C" void kernel_launch(void* const* d_in, const int* in_sizes, int n_in,
                              void* d_out, int out_size, void* d_ws, size_t ws_size,
                              hipStream_t stream) {
    // inputs: 0=f (unused), 1=xy, 2=W1, 3=b1, 4=W2, 5=b2 (unused by Hessian)
    const float* xy = (const float*)d_in[1];
    const float* W1 = (const float*)d_in[2];
    const float* b1 = (const float*)d_in[3];
    const float* W2 = (const float*)d_in[4];
    float4* tabA = (float4*)d_ws;                        // 1600 B
    float*  tabK = (float*)((char*)d_ws + 1600);         // 400 B

    kDivFree_prep<<<1, 128, 0, stream>>>(W1, b1, W2, tabA, tabK);
    kDivFree_main<<<NPTS / (BLK * PPT), BLK, 0, stream>>>(
        (const float2*)xy, tabA, (const float4*)tabK, (float2*)d_out);
}

// Round 8
// 23.648 us; speedup vs baseline: 1.2449x; 1.1537x over previous
//
#include <hip/hip_runtime.h>

#define NPTS 524288
#define HID 100
#define PPT 4      // points per thread: ILP for exp/rcp chains + table amortization
#define BLK 256

// Single fused kernel. Each block builds the per-j constant table in LDS
// (redundant across blocks — 100 threads, ~10 ops, one barrier; removes the
// serialized 1-block prep dispatch that cost ~5-8us of the 27us):
//   sA[j] = { w1x*2log2e, w1y*2log2e, b1*2log2e, ku }
//   sKf[j] = kv   (read back as float4 per 4 j)
// ku = 2*W2*w1y*(w1x - w1y)   (u = Hxy - Hyy accumulates s*ku)
// kv = 2*W2*w1x*(w1y - w1x)   (v = Hxy - Hxx accumulates s*kv)
// where s = h^3 - h, h = tanh(xy.W1 + b1).

__device__ __forceinline__ float fexp2(float x) {
    float r;
    asm("v_exp_f32 %0, %1" : "=v"(r) : "v"(x));
    return r;
}

__device__ __forceinline__ float tanh_s(float a2l) {
    // input: 2*log2(e)*a; returns s = h^3 - h, h = tanh(a)
    float t = fexp2(a2l);                        // e^{2a} (inf-safe: s->0)
    float r = __builtin_amdgcn_rcpf(t + 1.0f);
    float h = fmaf(-2.0f, r, 1.0f);              // tanh
    return h * fmaf(h, h, -1.0f);                // h^3 - h
}

__global__ void __launch_bounds__(BLK)
kDivFree_main(const float2* __restrict__ xy,
              const float* __restrict__ W1,
              const float* __restrict__ b1,
              const float* __restrict__ W2,
              float2* __restrict__ out) {
    __shared__ float4 sA[HID];          // 1600 B
    __shared__ float  sKf[HID];         // 400 B (padded to /4)

    int t = threadIdx.x;
    if (t < HID) {
        const float L2E2 = 2.8853900817779268f;  // 2*log2(e)
        float w1x = W1[t];            // W1[0][j]
        float w1y = W1[HID + t];      // W1[1][j]
        float w2  = W2[t];
        sA[t] = make_float4(w1x * L2E2, w1y * L2E2, b1[t] * L2E2,
                            2.0f * w2 * w1y * (w1x - w1y));
        sKf[t] = 2.0f * w2 * w1x * (w1y - w1x);
    }
    __syncthreads();

    const float4* sK4 = (const float4*)sKf;

    int base = blockIdx.x * (BLK * PPT) + threadIdx.x;
    float2 p[PPT];
    float  u[PPT], v[PPT];
#pragma unroll
    for (int k = 0; k < PPT; ++k) {
        p[k] = xy[base + k * BLK];
        u[k] = 0.0f;
        v[k] = 0.0f;
    }

    for (int j4 = 0; j4 < HID / 4; ++j4) {
        float4 K = sK4[j4];
        float kv[4] = {K.x, K.y, K.z, K.w};
#pragma unroll
        for (int jj = 0; jj < 4; ++jj) {
            float4 A = sA[j4 * 4 + jj];
#pragma unroll
            for (int k = 0; k < PPT; ++k) {
                float s = tanh_s(fmaf(p[k].x, A.x, fmaf(p[k].y, A.y, A.z)));
                u[k] = fmaf(s, A.w, u[k]);
                v[k] = fmaf(s, kv[jj], v[k]);
            }
        }
    }

#pragma unroll
    for (int k = 0; k < PPT; ++k)
        out[base + k * BLK] = make_float2(u[k], v[k]);
}

extern "C" void kernel_launch(void* const* d_in, const int* in_sizes, int n_in,
                              void* d_out, int out_size, void* d_ws, size_t ws_size,
                              hipStream_t stream) {
    // inputs: 0=f (unused), 1=xy, 2=W1, 3=b1, 4=W2, 5=b2 (unused by Hessian)
    const float* xy = (const float*)d_in[1];
    const float* W1 = (const float*)d_in[2];
    const float* b1 = (const float*)d_in[3];
    const float* W2 = (const float*)d_in[4];

    kDivFree_main<<<NPTS / (BLK * PPT), BLK, 0, stream>>>(
        (const float2*)xy, W1, b1, W2, (float2*)d_out);
}